// Round 2
// baseline (10939.107 us; speedup 1.0000x reference)
//
#include <hip/hip_runtime.h>

#define BB 64
#define HH 1024
#define SS 512

typedef __attribute__((ext_vector_type(8))) short short8;
typedef __attribute__((ext_vector_type(4))) float f32x4;

__device__ __forceinline__ unsigned short f2bf(float f) {
  union { float f; unsigned u; } v; v.f = f;
  unsigned r = v.u + 0x7fffu + ((v.u >> 16) & 1u);   // RNE
  return (unsigned short)(r >> 16);
}

// ---- prep: fp32 weights -> bf16; h0 -> bf16 buffer 0; optionally x -> bf16 ----
__global__ void gru_prep(const float* __restrict__ wih, const float* __restrict__ whh,
                         const float* __restrict__ h0, const float* __restrict__ x,
                         unsigned short* __restrict__ wih_bf,
                         unsigned short* __restrict__ whh_bf,
                         unsigned short* __restrict__ hbf,
                         unsigned short* __restrict__ xbf, int do_x) {
  const int NT = gridDim.x * blockDim.x;
  const int tid = blockIdx.x * blockDim.x + threadIdx.x;
  for (int i = tid; i < 3 * HH * HH; i += NT) {
    wih_bf[i] = f2bf(wih[i]);
    whh_bf[i] = f2bf(whh[i]);
  }
  for (int i = tid; i < BB * HH; i += NT) hbf[i] = f2bf(h0[i]);
  if (do_x)
    for (int i = tid; i < BB * SS * HH; i += NT) xbf[i] = f2bf(x[i]);
}

// ---- persistent GRU, regular launch + custom per-quarter barrier ----
// 256 WGs x 256 thr, 1 WG/CU. WG = (16 hidden cols c0) x (16-row batch quarter m0).
// K=1024 split across the 4 waves (256 each); weights register-resident.
__global__ __launch_bounds__(256, 1) void gru_main(
    const float* __restrict__ x, const unsigned short* __restrict__ xbf, const int use_xbf,
    const float* __restrict__ h0,
    const float* __restrict__ bih, const float* __restrict__ bhh,
    const unsigned short* __restrict__ wih_bf, const unsigned short* __restrict__ whh_bf,
    unsigned short* __restrict__ hbf, int* __restrict__ bar, float* __restrict__ out) {
  __shared__ float lds[2 * 4 * 6 * 64 * 4];   // [buf][wave][acc][lane][4] = 48 KB

  const int wg   = blockIdx.x;
  const int idx  = (wg >> 3) + (wg & 7) * 32;   // XCD swizzle: each XCD gets 8 colgroups x 4 quarters
  const int c0   = (idx >> 2) * 16;             // hidden colgroup base
  const int m0   = (idx & 3) * 16;              // batch quarter base
  const int q    = idx & 3;                     // barrier group
  const int wv   = threadIdx.x >> 6;
  const int ln   = threadIdx.x & 63;
  const int l15  = ln & 15;
  const int quad = ln >> 4;
  const int kb   = wv * 256 + quad * 8;         // wave K window + A/B frag offset

  // ---- register-resident weights: B-frag rows n=c0+l15, k = kb + kk*32 + e ----
  const unsigned short* wib = wih_bf + (size_t)(c0 + l15) * HH + kb;
  const unsigned short* whb = whh_bf + (size_t)(c0 + l15) * HH + kb;
  short8 Wi[3][8], Wh[3][8];
#pragma unroll
  for (int g = 0; g < 3; ++g)
#pragma unroll
    for (int kk = 0; kk < 8; ++kk) {
      Wi[g][kk] = *(const short8*)(wib + (size_t)g * HH * HH + kk * 32);
      Wh[g][kk] = *(const short8*)(whb + (size_t)g * HH * HH + kk * 32);
    }

  const int j = c0 + l15;                       // hidden col this lane owns (C/D col)
  const float br   = bih[j] + bhh[j];
  const float bz   = bih[HH + j] + bhh[HH + j];
  const float bi_n = bih[2 * HH + j];
  const float bh_n = bhh[2 * HH + j];

  // fp32 master h (wave 0 uses it; C/D layout rows m0+quad*4+i, col j)
  f32x4 hreg;
#pragma unroll
  for (int i = 0; i < 4; ++i) hreg[i] = h0[(m0 + quad * 4 + i) * HH + j];

  const float*          xfp   = x   + (size_t)(m0 + l15) * (SS * HH) + kb;
  const unsigned short* xbp   = xbf + (size_t)(m0 + l15) * (SS * HH) + kb;
  const unsigned short* hbase = hbf + (m0 + l15) * HH + kb;

  f32x4* ldsv = (f32x4*)lds;                    // buffer stride 4*6*64 = 1536

#pragma unroll 1
  for (int t = 0; t < SS; ++t) {
    const int buf = (t & 1) * 1536;

    // ---- h-independent half: x fragments + x-projection MFMAs ----
    short8 ax[8];
    if (use_xbf) {
      const unsigned short* xp = xbp + (size_t)t * HH;
#pragma unroll
      for (int kk = 0; kk < 8; ++kk) ax[kk] = *(const short8*)(xp + kk * 32);
    } else {
      const float* xp = xfp + (size_t)t * HH;
#pragma unroll
      for (int kk = 0; kk < 8; ++kk) {
        float4 xa = *(const float4*)(xp + kk * 32);
        float4 xb = *(const float4*)(xp + kk * 32 + 4);
        short8 v;
        v[0] = (short)f2bf(xa.x); v[1] = (short)f2bf(xa.y);
        v[2] = (short)f2bf(xa.z); v[3] = (short)f2bf(xa.w);
        v[4] = (short)f2bf(xb.x); v[5] = (short)f2bf(xb.y);
        v[6] = (short)f2bf(xb.z); v[7] = (short)f2bf(xb.w);
        ax[kk] = v;
      }
    }
    f32x4 a0 = {0.f, 0.f, 0.f, 0.f}, a1 = a0, a2 = a0;
#pragma unroll
    for (int kk = 0; kk < 8; ++kk) {
      a0 = __builtin_amdgcn_mfma_f32_16x16x32_bf16(ax[kk], Wi[0][kk], a0, 0, 0, 0);
      a1 = __builtin_amdgcn_mfma_f32_16x16x32_bf16(ax[kk], Wi[1][kk], a1, 0, 0, 0);
      a2 = __builtin_amdgcn_mfma_f32_16x16x32_bf16(ax[kk], Wi[2][kk], a2, 0, 0, 0);
    }
    ldsv[buf + (wv * 6 + 0) * 64 + ln] = a0;
    ldsv[buf + (wv * 6 + 1) * 64 + ln] = a1;
    ldsv[buf + (wv * 6 + 2) * 64 + ln] = a2;

    // ---- wait for h_t (produced at end of step t-1 by the 64 WGs of quarter q) ----
    if (t > 0 && threadIdx.x == 0) {
      while (__hip_atomic_load(&bar[(t - 1) * 4 + q], __ATOMIC_ACQUIRE,
                               __HIP_MEMORY_SCOPE_AGENT) < 64) { }
    }
    __syncthreads();   // releases WG after spin; also publishes x-partials in LDS

    // ---- h half ----
    const unsigned short* hp = hbase + (t & 1) * (BB * HH);
    f32x4 a3 = {0.f, 0.f, 0.f, 0.f}, a4 = a3, a5 = a3;
#pragma unroll
    for (int kk = 0; kk < 8; ++kk) {
      short8 ah = *(const short8*)(hp + kk * 32);
      a3 = __builtin_amdgcn_mfma_f32_16x16x32_bf16(ah, Wh[0][kk], a3, 0, 0, 0);
      a4 = __builtin_amdgcn_mfma_f32_16x16x32_bf16(ah, Wh[1][kk], a4, 0, 0, 0);
      a5 = __builtin_amdgcn_mfma_f32_16x16x32_bf16(ah, Wh[2][kk], a5, 0, 0, 0);
    }
    ldsv[buf + (wv * 6 + 3) * 64 + ln] = a3;
    ldsv[buf + (wv * 6 + 4) * 64 + ln] = a4;
    ldsv[buf + (wv * 6 + 5) * 64 + ln] = a5;
    __syncthreads();

    // ---- epilogue: wave 0 reduces K-partials, applies gates, stores ----
    if (wv == 0) {
      f32x4 s[6];
#pragma unroll
      for (int a = 0; a < 6; ++a)
        s[a] = ldsv[buf + (0 * 6 + a) * 64 + ln] + ldsv[buf + (1 * 6 + a) * 64 + ln] +
               ldsv[buf + (2 * 6 + a) * 64 + ln] + ldsv[buf + (3 * 6 + a) * 64 + ln];
      const int nxt = ((t + 1) & 1) * (BB * HH);
#pragma unroll
      for (int i = 0; i < 4; ++i) {
        const int b = m0 + quad * 4 + i;
        float r = 1.f / (1.f + __expf(-(s[0][i] + s[3][i] + br)));
        float z = 1.f / (1.f + __expf(-(s[1][i] + s[4][i] + bz)));
        float pre = s[2][i] + bi_n + r * (s[5][i] + bh_n);
        float e2 = __expf(2.f * pre);
        float n = 1.f - 2.f / (e2 + 1.f);       // tanh
        float hnew = (1.f - z) * n + z * hreg[i];
        hreg[i] = hnew;
        hbf[nxt + b * HH + j] = f2bf(hnew);
        out[(size_t)b * (SS * HH) + (size_t)t * HH + j] = hnew;
        if (t == SS - 1) out[(size_t)BB * SS * HH + b * HH + j] = hnew;  // hn
      }
      __threadfence();   // agent-scope release of h stores
      if (ln == 0)
        __hip_atomic_fetch_add(&bar[t * 4 + q], 1, __ATOMIC_RELEASE,
                               __HIP_MEMORY_SCOPE_AGENT);
    }
    // next iteration writes LDS buffer (t+1)&1 — no tail sync needed
  }
}

extern "C" void kernel_launch(void* const* d_in, const int* in_sizes, int n_in,
                              void* d_out, int out_size, void* d_ws, size_t ws_size,
                              hipStream_t stream) {
  const float* x   = (const float*)d_in[0];
  const float* h0  = (const float*)d_in[1];
  const float* wih = (const float*)d_in[2];
  const float* whh = (const float*)d_in[3];
  const float* bih = (const float*)d_in[4];
  const float* bhh = (const float*)d_in[5];
  float* out = (float*)d_out;

  char* ws = (char*)d_ws;
  const size_t off_whh = 6291456;            // 3*1024*1024*2
  const size_t off_h   = 12582912;
  const size_t off_bar = 12845056;           // after 2 h buffers (262144 B)
  const size_t off_x   = 12853248;           // after barrier array (8192 B)
  const size_t need_x  = off_x + (size_t)BB * SS * HH * 2;   // ~80 MB

  unsigned short* wih_bf = (unsigned short*)ws;
  unsigned short* whh_bf = (unsigned short*)(ws + off_whh);
  unsigned short* hbf    = (unsigned short*)(ws + off_h);
  int*            bar    = (int*)(ws + off_bar);
  unsigned short* xbf    = (unsigned short*)(ws + off_x);
  const int use_xbf = (ws_size >= need_x) ? 1 : 0;

  hipMemsetAsync(bar, 0, 8192, stream);      // barrier counters must start at 0 (ws is poisoned)
  hipLaunchKernelGGL(gru_prep, dim3(2048), dim3(256), 0, stream,
                     wih, whh, h0, x, wih_bf, whh_bf, hbf, xbf, use_xbf);
  hipLaunchKernelGGL(gru_main, dim3(256), dim3(256), 0, stream,
                     x, xbf, use_xbf, h0, bih, bhh, wih_bf, whh_bf, hbf, bar, out);
}

// Round 3
// 6894.077 us; speedup vs baseline: 1.5867x; 1.5867x over previous
//
#include <hip/hip_runtime.h>

#define BB 64
#define HH 1024
#define SS 512

typedef __attribute__((ext_vector_type(8))) short short8;
typedef __attribute__((ext_vector_type(4))) float f32x4;
typedef unsigned long long u64;

__device__ __forceinline__ unsigned short f2bf(float f) {
  union { float f; unsigned u; } v; v.f = f;
  unsigned r = v.u + 0x7fffu + ((v.u >> 16) & 1u);   // RNE
  return (unsigned short)(r >> 16);
}

// ---- prep: fp32 weights -> bf16; h0 -> bf16 buffer 0; optionally x -> bf16 ----
__global__ void gru_prep(const float* __restrict__ wih, const float* __restrict__ whh,
                         const float* __restrict__ h0, const float* __restrict__ x,
                         unsigned short* __restrict__ wih_bf,
                         unsigned short* __restrict__ whh_bf,
                         unsigned short* __restrict__ hbf,
                         unsigned short* __restrict__ xbf, int do_x) {
  const int NT = gridDim.x * blockDim.x;
  const int tid = blockIdx.x * blockDim.x + threadIdx.x;
  for (int i = tid; i < 3 * HH * HH; i += NT) {
    wih_bf[i] = f2bf(wih[i]);
    whh_bf[i] = f2bf(whh[i]);
  }
  for (int i = tid; i < BB * HH; i += NT) hbf[i] = f2bf(h0[i]);
  if (do_x)
    for (int i = tid; i < BB * SS * HH; i += NT) xbf[i] = f2bf(x[i]);
}

// ---- persistent GRU ----
// 256 WGs x 256 thr, 1 WG/CU. WG = (16 hidden cols c0) x (16-row batch quarter m0).
// K=1024 split across 4 waves; weights register-resident.
// Cross-WG h exchange uses ONLY sc1-bypassing relaxed atomics (no L2 inv/wb in
// steady state); flag add carries RELEASE (vmcnt drain) so h is at the
// coherence point before the count ticks.
__global__ __launch_bounds__(256, 1) void gru_main(
    const float* __restrict__ x, const unsigned short* __restrict__ xbf, const int use_xbf,
    const float* __restrict__ h0,
    const float* __restrict__ bih, const float* __restrict__ bhh,
    const unsigned short* __restrict__ wih_bf, const unsigned short* __restrict__ whh_bf,
    unsigned short* __restrict__ hbf, int* __restrict__ bar, float* __restrict__ out) {
  __shared__ float lds[2 * 4 * 6 * 64 * 4];   // [buf][wave][acc][lane][4] = 48 KB
  __shared__ unsigned short hstage[16 * 16];  // epilogue transpose staging

  const int wg   = blockIdx.x;
  const int idx  = (wg >> 3) + (wg & 7) * 32;   // XCD swizzle (perf heuristic only)
  const int c0   = (idx >> 2) * 16;             // hidden colgroup base
  const int m0   = (idx & 3) * 16;              // batch quarter base
  const int q    = idx & 3;                     // barrier group
  const int wv   = threadIdx.x >> 6;
  const int ln   = threadIdx.x & 63;
  const int l15  = ln & 15;
  const int quad = ln >> 4;
  const int kb   = wv * 256 + quad * 8;         // wave K window + A/B frag offset

  // ---- register-resident weights: B-frag rows n=c0+l15, k = kb + kk*32 + e ----
  const unsigned short* wib = wih_bf + (size_t)(c0 + l15) * HH + kb;
  const unsigned short* whb = whh_bf + (size_t)(c0 + l15) * HH + kb;
  short8 Wi[3][8], Wh[3][8];
#pragma unroll
  for (int g = 0; g < 3; ++g)
#pragma unroll
    for (int kk = 0; kk < 8; ++kk) {
      Wi[g][kk] = *(const short8*)(wib + (size_t)g * HH * HH + kk * 32);
      Wh[g][kk] = *(const short8*)(whb + (size_t)g * HH * HH + kk * 32);
    }

  const int j = c0 + l15;                       // hidden col this lane owns (C/D col)
  const float br   = bih[j] + bhh[j];
  const float bz   = bih[HH + j] + bhh[HH + j];
  const float bi_n = bih[2 * HH + j];
  const float bh_n = bhh[2 * HH + j];

  // fp32 master h (wave 0; C/D layout rows m0+quad*4+i, col j)
  f32x4 hreg;
#pragma unroll
  for (int i = 0; i < 4; ++i) hreg[i] = h0[(m0 + quad * 4 + i) * HH + j];

  const float*          xfp = x   + (size_t)(m0 + l15) * (SS * HH) + kb;
  const unsigned short* xbp = xbf + (size_t)(m0 + l15) * (SS * HH) + kb;

  f32x4* ldsv = (f32x4*)lds;                    // buffer stride 4*6*64 = 1536

#pragma unroll 1
  for (int t = 0; t < SS; ++t) {
    const int buf = (t & 1) * 1536;

    // ---- h-independent half: x fragments + x-projection MFMAs ----
    short8 ax[8];
    if (use_xbf) {
      const unsigned short* xp = xbp + (size_t)t * HH;
#pragma unroll
      for (int kk = 0; kk < 8; ++kk) ax[kk] = *(const short8*)(xp + kk * 32);
    } else {
      const float* xp = xfp + (size_t)t * HH;
#pragma unroll
      for (int kk = 0; kk < 8; ++kk) {
        float4 xa = *(const float4*)(xp + kk * 32);
        float4 xb = *(const float4*)(xp + kk * 32 + 4);
        short8 v;
        v[0] = (short)f2bf(xa.x); v[1] = (short)f2bf(xa.y);
        v[2] = (short)f2bf(xa.z); v[3] = (short)f2bf(xa.w);
        v[4] = (short)f2bf(xb.x); v[5] = (short)f2bf(xb.y);
        v[6] = (short)f2bf(xb.z); v[7] = (short)f2bf(xb.w);
        ax[kk] = v;
      }
    }
    f32x4 a0 = {0.f, 0.f, 0.f, 0.f}, a1 = a0, a2 = a0;
#pragma unroll
    for (int kk = 0; kk < 8; ++kk) {
      a0 = __builtin_amdgcn_mfma_f32_16x16x32_bf16(ax[kk], Wi[0][kk], a0, 0, 0, 0);
      a1 = __builtin_amdgcn_mfma_f32_16x16x32_bf16(ax[kk], Wi[1][kk], a1, 0, 0, 0);
      a2 = __builtin_amdgcn_mfma_f32_16x16x32_bf16(ax[kk], Wi[2][kk], a2, 0, 0, 0);
    }
    ldsv[buf + (wv * 6 + 0) * 64 + ln] = a0;
    ldsv[buf + (wv * 6 + 1) * 64 + ln] = a1;
    ldsv[buf + (wv * 6 + 2) * 64 + ln] = a2;

    // ---- wait for h_t: RELAXED polls (no L2 invalidate), control-dep orders
    // the bypassing h loads after the flag observation ----
    if (t > 0 && threadIdx.x == 0) {
      while (__hip_atomic_load(&bar[(t - 1) * 4 + q], __ATOMIC_RELAXED,
                               __HIP_MEMORY_SCOPE_AGENT) < 64)
        __builtin_amdgcn_s_sleep(1);
    }
    __syncthreads();   // releases WG after spin; also publishes x-partials in LDS

    // ---- h half: bypassing (agent-scope relaxed) 8B loads, straight from L3 ----
    const u64* hq = (const u64*)(hbf + (t & 1) * (BB * HH)) +
                    (((m0 + l15) * HH + kb) >> 2);
    f32x4 a3 = {0.f, 0.f, 0.f, 0.f}, a4 = a3, a5 = a3;
#pragma unroll
    for (int kk = 0; kk < 8; ++kk) {
      union { u64 u[2]; short8 s; } uu;
      uu.u[0] = __hip_atomic_load(hq + kk * 8 + 0, __ATOMIC_RELAXED,
                                  __HIP_MEMORY_SCOPE_AGENT);
      uu.u[1] = __hip_atomic_load(hq + kk * 8 + 1, __ATOMIC_RELAXED,
                                  __HIP_MEMORY_SCOPE_AGENT);
      short8 ah = uu.s;
      a3 = __builtin_amdgcn_mfma_f32_16x16x32_bf16(ah, Wh[0][kk], a3, 0, 0, 0);
      a4 = __builtin_amdgcn_mfma_f32_16x16x32_bf16(ah, Wh[1][kk], a4, 0, 0, 0);
      a5 = __builtin_amdgcn_mfma_f32_16x16x32_bf16(ah, Wh[2][kk], a5, 0, 0, 0);
    }
    ldsv[buf + (wv * 6 + 3) * 64 + ln] = a3;
    ldsv[buf + (wv * 6 + 4) * 64 + ln] = a4;
    ldsv[buf + (wv * 6 + 5) * 64 + ln] = a5;
    __syncthreads();

    // ---- epilogue: wave 0 reduces K-partials, applies gates, stores ----
    if (wv == 0) {
      f32x4 s[6];
#pragma unroll
      for (int a = 0; a < 6; ++a)
        s[a] = ldsv[buf + (0 * 6 + a) * 64 + ln] + ldsv[buf + (1 * 6 + a) * 64 + ln] +
               ldsv[buf + (2 * 6 + a) * 64 + ln] + ldsv[buf + (3 * 6 + a) * 64 + ln];
#pragma unroll
      for (int i = 0; i < 4; ++i) {
        const int b = m0 + quad * 4 + i;
        float r = 1.f / (1.f + __expf(-(s[0][i] + s[3][i] + br)));
        float z = 1.f / (1.f + __expf(-(s[1][i] + s[4][i] + bz)));
        float pre = s[2][i] + bi_n + r * (s[5][i] + bh_n);
        float e2 = __expf(2.f * pre);
        float n = 1.f - 2.f / (e2 + 1.f);       // tanh
        float hnew = (1.f - z) * n + z * hreg[i];
        hreg[i] = hnew;
        hstage[(quad * 4 + i) * 16 + l15] = f2bf(hnew);   // transpose staging
        __builtin_nontemporal_store(hnew, &out[(size_t)b * (SS * HH) + (size_t)t * HH + j]);
        if (t == SS - 1)
          __builtin_nontemporal_store(hnew, &out[(size_t)BB * SS * HH + b * HH + j]);
      }
      // pack 4 contiguous bf16 per lane, publish via bypassing atomic store
      const int nxt = ((t + 1) & 1) * (BB * HH);
      u64 pk = *(const u64*)&hstage[(ln >> 2) * 16 + (ln & 3) * 4];
      u64* hdst = (u64*)(hbf + nxt) + (((m0 + (ln >> 2)) * HH + c0) >> 2) + (ln & 3);
      __hip_atomic_store(hdst, pk, __ATOMIC_RELAXED, __HIP_MEMORY_SCOPE_AGENT);
      if (ln == 0)
        __hip_atomic_fetch_add(&bar[t * 4 + q], 1, __ATOMIC_RELEASE,
                               __HIP_MEMORY_SCOPE_AGENT);   // RELEASE: drains vmcnt first
    }
    // next iteration uses the other LDS buffer — no tail sync needed
  }
}

extern "C" void kernel_launch(void* const* d_in, const int* in_sizes, int n_in,
                              void* d_out, int out_size, void* d_ws, size_t ws_size,
                              hipStream_t stream) {
  const float* x   = (const float*)d_in[0];
  const float* h0  = (const float*)d_in[1];
  const float* wih = (const float*)d_in[2];
  const float* whh = (const float*)d_in[3];
  const float* bih = (const float*)d_in[4];
  const float* bhh = (const float*)d_in[5];
  float* out = (float*)d_out;

  char* ws = (char*)d_ws;
  const size_t off_whh = 6291456;            // 3*1024*1024*2
  const size_t off_h   = 12582912;
  const size_t off_bar = 12845056;           // after 2 h buffers (262144 B)
  const size_t off_x   = 12853248;           // after barrier array (8192 B)
  const size_t need_x  = off_x + (size_t)BB * SS * HH * 2;   // ~80 MB

  unsigned short* wih_bf = (unsigned short*)ws;
  unsigned short* whh_bf = (unsigned short*)(ws + off_whh);
  unsigned short* hbf    = (unsigned short*)(ws + off_h);
  int*            bar    = (int*)(ws + off_bar);
  unsigned short* xbf    = (unsigned short*)(ws + off_x);
  const int use_xbf = (ws_size >= need_x) ? 1 : 0;

  hipMemsetAsync(bar, 0, 8192, stream);      // ws is poisoned; counters must start at 0
  hipLaunchKernelGGL(gru_prep, dim3(2048), dim3(256), 0, stream,
                     wih, whh, h0, x, wih_bf, whh_bf, hbf, xbf, use_xbf);
  hipLaunchKernelGGL(gru_main, dim3(256), dim3(256), 0, stream,
                     x, xbf, use_xbf, h0, bih, bhh, wih_bf, whh_bf, hbf, bar, out);
}